// Round 7
// baseline (1026.021 us; speedup 1.0000x reference)
//
#include <hip/hip_runtime.h>
#include <math.h>

#define NB 16
#define INW 256
#define GN 100
#define NV (GN*GN)          // 10000
#define NPROB (NB*2)        // 32
#define K_TOP 20
#define HSZ 8192
#define HMASK (HSZ-1)
#define EMPTYK 0xFFFFFFFFu
#define KB 16               // rank buckets per problem
#define RCAP 5120           // max regions per problem
#define MYCAP 512           // max edges per bucket (= ceil(HSZ/KB))
#define LISTCAP 6144        // max bars per problem (bars < R <= RCAP)

// ws byte offsets
#define OFF_RES   0               // NB*NV f32 = 640000
#define OFF_LAB   640000          // NPROB*NV u16
#define OFF_DENSE 1280000         // NPROB*NV u16
#define OFF_D2B   1920000         // NPROB*RCAP f32 (birth value per dense id)
#define OFF_EDGES 2575360         // NPROB*HSZ u64
#define OFF_ECNT  4672512         // NPROB u32
#define OFF_RCNT  4672640         // NPROB u32
#define OFF_QUANT 4672768         // NPROB*16 u64 splitters
#define OFF_LCNT  4676864         // NPROB u32
#define OFF_LIST  4676992         // NPROB*LISTCAP f32
#define OFF_PART  5463424         // NPROB f32

__device__ __forceinline__ int imin(int a, int b){ return a < b ? a : b; }
__device__ __forceinline__ int imax(int a, int b){ return a > b ? a : b; }

__device__ __forceinline__ unsigned mono32(float f){
  unsigned b = __float_as_uint(f);
  return (b & 0x80000000u) ? ~b : (b | 0x80000000u);
}
__device__ __forceinline__ float unmono(unsigned m){
  unsigned b = (m & 0x80000000u) ? (m ^ 0x80000000u) : ~m;
  return __uint_as_float(b);
}

// keys-cubic a=-0.5 weights for one output coord (renormalized over valid taps)
__device__ __forceinline__ void cub_w(int i, int& j0, float w[4]) {
  double inv = (double)INW / (double)GN;
  double sf  = ((double)i + 0.5) * inv - 0.5;
  j0 = (int)floor(sf) - 1;
  double wd[4]; double s = 0.0;
  #pragma unroll
  for (int k = 0; k < 4; ++k) {
    int j = j0 + k;
    double t = fabs(sf - (double)j);
    double v;
    if (t < 1.0)      v = ((1.5*t - 2.5)*t)*t + 1.0;
    else if (t < 2.0) v = ((-0.5*t + 2.5)*t - 4.0)*t + 2.0;
    else              v = 0.0;
    if (j < 0 || j >= INW) v = 0.0;
    wd[k] = v; s += v;
  }
  #pragma unroll
  for (int k = 0; k < 4; ++k) w[k] = (float)(wd[k] / s);
}

// ---------------------------------------------------------------------------
// Kernel 1: separable bicubic resize 256x256 -> 100x100
// ---------------------------------------------------------------------------
__global__ __launch_bounds__(256) void resize_k(const float* __restrict__ in, float* ws) {
  float* outp = (float*)((char*)ws + OFF_RES);
  int idx = blockIdx.x * 256 + threadIdx.x;
  if (idx >= NB * NV) return;
  int b = idx / NV; int rem = idx - b * NV;
  int i = rem / GN; int j = rem - i * GN;
  const float* img = in + (size_t)b * INW * INW;
  int r0, c0; float wr[4], wc[4];
  cub_w(i, r0, wr);
  cub_w(j, c0, wc);
  float acc = 0.f;
  #pragma unroll
  for (int kr = 0; kr < 4; ++kr) {
    int rr = imin(imax(r0 + kr, 0), INW - 1);
    const float* row = img + rr * INW;
    int c0c = imin(imax(c0 + 0, 0), INW - 1);
    int c1c = imin(imax(c0 + 1, 0), INW - 1);
    int c2c = imin(imax(c0 + 2, 0), INW - 1);
    int c3c = imin(imax(c0 + 3, 0), INW - 1);
    float rs = wc[0]*row[c0c] + wc[1]*row[c1c] + wc[2]*row[c2c] + wc[3]*row[c3c];
    acc += wr[kr] * rs;
  }
  outp[idx] = acc;
}

// ---------------------------------------------------------------------------
// Kernel 2: watershed labels + dense rename in DESC elder order.
// dense id = rank of region peak under (key desc, vertex-id asc) =>
// elder rule becomes "smaller dense id wins" and UF min-root IS the elder.
// ---------------------------------------------------------------------------
__global__ __launch_bounds__(256) void label_rename_k(float* ws) {
  __shared__ unsigned sm[NV];                 // 40KB
  __shared__ unsigned short lab[NV];          // 20KB
  __shared__ unsigned cnt[256];
  __shared__ unsigned rootv[RCAP];            // 20KB
  __shared__ unsigned long long rord[RCAP];   // 40KB
  int p = blockIdx.x, samp = p >> 1, neg = p & 1, tid = threadIdx.x;
  const float* res = (const float*)((const char*)ws + OFF_RES) + samp * NV;
  unsigned short* glab = (unsigned short*)((char*)ws + OFF_LAB) + (size_t)p * NV;
  unsigned short* dense = (unsigned short*)((char*)ws + OFF_DENSE) + (size_t)p * NV;
  float* d2b = (float*)((char*)ws + OFF_D2B) + (size_t)p * RCAP;
  unsigned* rcnt = (unsigned*)((char*)ws + OFF_RCNT);
  float sgn = neg ? -1.f : 1.f;
  for (int i = tid; i < NV; i += 256) sm[i] = mono32(sgn * res[i]);
  __syncthreads();
  const int nd = neg ? 4 : 6;
  for (int v = tid; v < NV; v += 256) {
    int r = v / GN, c = v - r * GN;
    unsigned long long best = ((unsigned long long)sm[v] << 32) | (unsigned)~(unsigned)v;
    unsigned bi = (unsigned)v;
    bool cb[6] = { c < GN-1, c > 0, r < GN-1, r > 0,
                   (r < GN-1) && (c < GN-1), (r > 0) && (c > 0) };
    int  off[6] = { 1, -1, GN, -GN, GN+1, -(GN+1) };
    #pragma unroll
    for (int d = 0; d < 6; ++d) {
      if (d < nd && cb[d]) {
        unsigned y = (unsigned)(v + off[d]);
        unsigned long long o = ((unsigned long long)sm[y] << 32) | (unsigned)~y;
        if (o > best) { best = o; bi = y; }
      }
    }
    lab[v] = (unsigned short)bi;
  }
  __syncthreads();
  for (int v = tid; v < NV; v += 256) {
    unsigned r = lab[v];
    while (1) { unsigned n = lab[r]; if (n == r) break; r = n; }
    lab[v] = (unsigned short)r;
    glab[v] = (unsigned short)r;
  }
  __syncthreads();
  // compact roots
  unsigned my = 0;
  for (int v = tid; v < NV; v += 256) if (lab[v] == (unsigned short)v) ++my;
  cnt[tid] = my;
  __syncthreads();
  for (int off = 1; off < 256; off <<= 1) {
    unsigned t = (tid >= off) ? cnt[tid - off] : 0u;
    __syncthreads();
    cnt[tid] += t;
    __syncthreads();
  }
  unsigned base = cnt[tid] - my;
  for (int v = tid; v < NV; v += 256) {
    if (lab[v] == (unsigned short)v) {
      if (base < RCAP) {
        rootv[base] = (unsigned)v;
        rord[base] = ((unsigned long long)sm[v] << 32) | (unsigned)~(unsigned)v;
      }
      ++base;
    }
  }
  __syncthreads();
  unsigned R = cnt[255]; if (R > RCAP) R = RCAP;
  if (tid == 0) rcnt[p] = R;
  // rank roots desc (rords unique) -> dense id = elder rank
  for (unsigned i = tid; i < R; i += 256) {
    unsigned long long oi = rord[i];
    unsigned r = 0;
    for (unsigned j = 0; j < R; ++j) r += (rord[j] > oi) ? 1u : 0u;
    dense[rootv[i]] = (unsigned short)r;
    d2b[r] = unmono((unsigned)(oi >> 32));     // birth value of this peak
  }
}

// ---------------------------------------------------------------------------
// Kernel 3: boundary-edge hashing (dense pids, u32 events) + compaction
// ---------------------------------------------------------------------------
__global__ __launch_bounds__(256) void hash_k(float* ws) {
  __shared__ unsigned sm[NV];
  __shared__ unsigned hkey[HSZ];
  __shared__ unsigned hval[HSZ];
  __shared__ unsigned short lab[NV];
  __shared__ unsigned short dn[NV];
  __shared__ unsigned cnt[256];
  int p = blockIdx.x, samp = p >> 1, neg = p & 1, tid = threadIdx.x;
  const float* res = (const float*)((const char*)ws + OFF_RES) + samp * NV;
  const unsigned short* glab = (const unsigned short*)((const char*)ws + OFF_LAB) + (size_t)p * NV;
  const unsigned short* gdense = (const unsigned short*)((const char*)ws + OFF_DENSE) + (size_t)p * NV;
  unsigned long long* gedges = (unsigned long long*)((char*)ws + OFF_EDGES) + (size_t)p * HSZ;
  unsigned* ecnt = (unsigned*)((char*)ws + OFF_ECNT);
  unsigned* lcnt = (unsigned*)((char*)ws + OFF_LCNT);
  unsigned long long* quant = (unsigned long long*)((char*)ws + OFF_QUANT) + p * 16;
  float sgn = neg ? -1.f : 1.f;
  for (int i = tid; i < NV; i += 256) {
    sm[i] = mono32(sgn * res[i]); lab[i] = glab[i]; dn[i] = gdense[i];
  }
  for (int s = tid; s < HSZ; s += 256) { hkey[s] = EMPTYK; hval[s] = 0u; }
  if (tid == 0) lcnt[p] = 0u;
  if (tid < 16) quant[tid] = (tid == 0) ? ~0ull : 0ull;
  __syncthreads();
  for (int v = tid; v < NV; v += 256) {
    int r = v / GN, c = v - r * GN;
    unsigned a = lab[v];
    unsigned sv = sm[v];
    bool vb[3] = { c < GN-1, r < GN-1, (!neg) && (r < GN-1) && (c < GN-1) };
    int  vo[3] = { 1, GN, GN+1 };
    #pragma unroll
    for (int d = 0; d < 3; ++d) {
      if (vb[d]) {
        unsigned w = (unsigned)(v + vo[d]);
        unsigned b = lab[w];
        if (a != b) {
          unsigned sw = sm[w];
          unsigned ev = (sv < sw) ? sv : sw;
          unsigned da = dn[a], db = dn[b];
          unsigned dlo = (da < db) ? da : db, dhi = (da < db) ? db : da;
          unsigned pid = (dlo << 16) | dhi;
          unsigned h = (pid * 2654435761u) >> 19;
          for (int pr2 = 0; pr2 < HSZ; ++pr2) {
            unsigned k = hkey[h];
            if (k == EMPTYK) {
              unsigned old = atomicCAS(&hkey[h], EMPTYK, pid);
              k = (old == EMPTYK) ? pid : old;
            }
            if (k == pid) { atomicMax(&hval[h], ev); break; }
            h = (h + 1) & HMASK;
          }
        }
      }
    }
  }
  __syncthreads();
  unsigned my = 0;
  for (int s = tid; s < HSZ; s += 256) if (hkey[s] != EMPTYK) ++my;
  cnt[tid] = my;
  __syncthreads();
  for (int off = 1; off < 256; off <<= 1) {
    unsigned t = (tid >= off) ? cnt[tid - off] : 0u;
    __syncthreads();
    cnt[tid] += t;
    __syncthreads();
  }
  unsigned base = cnt[tid] - my;
  for (int s = tid; s < HSZ; s += 256) {
    if (hkey[s] != EMPTYK) {
      gedges[base++] = ((unsigned long long)hval[s] << 32) | hkey[s];
    }
  }
  if (tid == 255) ecnt[p] = cnt[255];
}

// ---------------------------------------------------------------------------
// Kernel 4: exact rank-quantile splitters. 16 slices/problem; items unique
// u64 => rank(x) = #{y > x}. Thread holding rank m*chunk writes quant[m].
// ---------------------------------------------------------------------------
__global__ __launch_bounds__(256) void quantile_k(float* ws) {
  __shared__ unsigned long long items[HSZ];   // 64KB
  int p = blockIdx.x / KB, sl = blockIdx.x % KB, tid = threadIdx.x;
  const unsigned long long* gedges = (const unsigned long long*)((const char*)ws + OFF_EDGES) + (size_t)p * HSZ;
  const unsigned* ecnt = (const unsigned*)((const char*)ws + OFF_ECNT);
  unsigned long long* quant = (unsigned long long*)((char*)ws + OFF_QUANT) + p * 16;
  unsigned E = ecnt[p]; if (E > HSZ) E = HSZ;
  for (unsigned i = tid; i < E; i += 256) items[i] = gedges[i];
  __syncthreads();
  unsigned chunk = (E + KB - 1) / KB;
  unsigned base = sl * chunk;
  for (unsigned e = base + tid; e < base + chunk && e < E; e += 256) {
    unsigned long long x = items[e];
    unsigned r = 0;
    for (unsigned j = 0; j < E; ++j) r += (items[j] > x) ? 1u : 0u;
    if (r >= chunk && (r % chunk) == 0) {
      unsigned m = r / chunk;
      if (m < KB) quant[m] = x;
    }
  }
}

// ---------------------------------------------------------------------------
// Kernel 5: bucketed elder-rule Kruskal. One block per (problem, bucket).
// prefix = {item > quant[bk]} streamed from L2 each CC round (order-free);
// own = rank range (quant[bk+1], quant[bk]], locally rank-sorted (<=512);
// UF min-root == elder peak (dense ids are elder ranks).
// ---------------------------------------------------------------------------
__global__ __launch_bounds__(256) void kruskal_bucket_k(float* ws) {
  __shared__ unsigned long long my[MYCAP];      // 4KB
  __shared__ unsigned long long my2[MYCAP + 1]; // 4KB
  __shared__ unsigned par[RCAP];                // 20KB
  __shared__ float birth[RCAP];                 // 20KB
  __shared__ unsigned mycnt;
  __shared__ int flag;
  int p = blockIdx.x / KB, bk = blockIdx.x % KB, tid = threadIdx.x;
  const unsigned long long* gedges = (const unsigned long long*)((const char*)ws + OFF_EDGES) + (size_t)p * HSZ;
  const float* d2b = (const float*)((const char*)ws + OFF_D2B) + (size_t)p * RCAP;
  const unsigned* ecnt = (const unsigned*)((const char*)ws + OFF_ECNT);
  const unsigned* rcnt = (const unsigned*)((const char*)ws + OFF_RCNT);
  const unsigned long long* quant = (const unsigned long long*)((const char*)ws + OFF_QUANT) + p * 16;
  unsigned* lcnt = (unsigned*)((char*)ws + OFF_LCNT);
  float* glist = (float*)((char*)ws + OFF_LIST) + (size_t)p * LISTCAP;
  unsigned E = ecnt[p]; if (E > HSZ) E = HSZ;
  unsigned R = rcnt[p]; if (R > RCAP) R = RCAP;
  unsigned long long qup = quant[bk];
  unsigned long long qdn = (bk == KB-1) ? 0ull : quant[bk + 1];
  if (tid == 0) mycnt = 0;
  for (unsigned d = tid; d < R; d += 256) { par[d] = d; birth[d] = d2b[d]; }
  __syncthreads();
  // gather own edges
  for (unsigned e = tid; e < E; e += 256) {
    unsigned long long it = gedges[e];
    if (it <= qup && it > qdn) {
      unsigned k = atomicAdd(&mycnt, 1u);
      my[k] = it;
    }
  }
  __syncthreads();
  unsigned mc = mycnt;
  if (tid == 0) my2[mc] = 0ull;
  // local rank sort desc (items unique)
  for (unsigned i = tid; i < mc; i += 256) {
    unsigned long long x = my[i];
    unsigned r = 0;
    for (unsigned j = 0; j < mc; ++j) r += (my[j] > x) ? 1u : 0u;
    my2[r] = x;
  }
  // parallel CC over prefix set (streamed from global/L2)
  while (1) {
    if (tid == 0) flag = 0;
    __syncthreads();
    for (unsigned e = tid; e < E; e += 256) {
      unsigned long long it = gedges[e];
      if (it > qup) {
        unsigned pid = (unsigned)it;
        unsigned a = pid >> 16, b = pid & 0xffffu;
        unsigned ra = a; while (par[ra] != ra) ra = par[ra];
        unsigned rb = b; while (par[rb] != rb) rb = par[rb];
        if (ra != rb) {
          unsigned mn = (ra < rb) ? ra : rb, mx = (ra < rb) ? rb : ra;
          atomicMin(&par[mx], mn);
          flag = 1;
        }
      }
    }
    __syncthreads();
    if (!flag) break;
    for (unsigned d = tid; d < R; d += 256) {
      unsigned r = d; while (par[r] != r) r = par[r];
      par[d] = r;
    }
    __syncthreads();
  }
  // serial Kruskal over own sorted edges; winner = min dense id (elder)
  if (tid != 0) return;
  unsigned long long it = my2[0];
  for (unsigned e = 0; e < mc; ++e) {
    unsigned long long nx = my2[e + 1];
    unsigned ev = (unsigned)(it >> 32);
    unsigned pid = (unsigned)it;
    unsigned ca = pid >> 16, cb = pid & 0xffffu;
    while (1) {
      unsigned pa = par[ca], pb = par[cb];
      bool da = (pa == ca), db = (pb == cb);
      if (da && db) break;
      unsigned ga = par[pa], gb = par[pb];
      if (!da) { par[ca] = ga; ca = ga; }
      if (!db) { par[cb] = gb; cb = gb; }
    }
    if (ca != cb) {
      unsigned win = (ca < cb) ? ca : cb;
      unsigned los = (ca < cb) ? cb : ca;
      float bar = birth[los] - unmono(ev);
      unsigned idx = atomicAdd(&lcnt[p], 1u);
      if (idx < LISTCAP) glist[idx] = bar;
      par[los] = win;
    }
    it = nx;
  }
}

// ---------------------------------------------------------------------------
// Kernel 6: per-problem top-20 over compact bar list -> partial[p]
// ---------------------------------------------------------------------------
__global__ __launch_bounds__(256) void topk_k(float* ws) {
  __shared__ float sl[LISTCAP];
  __shared__ float rv[256];
  __shared__ int   ri[256];
  int p = blockIdx.x, tid = threadIdx.x;
  const float* glist = (const float*)((const char*)ws + OFF_LIST) + (size_t)p * LISTCAP;
  const unsigned* lcnt = (const unsigned*)((const char*)ws + OFF_LCNT);
  float* part = (float*)((char*)ws + OFF_PART);
  unsigned cnt = lcnt[p]; if (cnt > LISTCAP) cnt = LISTCAP;
  for (unsigned i = tid; i < cnt; i += 256) sl[i] = glist[i];
  __syncthreads();
  float acc = 0.f;
  for (int k = 0; k < K_TOP; ++k) {
    float mv = -1.f; int mi = LISTCAP;
    for (unsigned i = tid; i < cnt; i += 256) {
      float v = sl[i];
      if (v > mv) { mv = v; mi = (int)i; }
    }
    rv[tid] = mv; ri[tid] = mi;
    __syncthreads();
    for (int s = 128; s > 0; s >>= 1) {
      if (tid < s) {
        if (rv[tid+s] > rv[tid] || (rv[tid+s] == rv[tid] && ri[tid+s] < ri[tid])) {
          rv[tid] = rv[tid+s]; ri[tid] = ri[tid+s];
        }
      }
      __syncthreads();
    }
    if (tid == 0) {
      float best = rv[0] > 0.f ? rv[0] : 0.f;   // pad with zeros like reference
      float sgnk = (k < 5) ? -1.f : 1.f;
      acc += sgnk * best * best;
      if (ri[0] < LISTCAP) sl[ri[0]] = -2.f;
    }
    __syncthreads();
  }
  if (tid == 0) part[p] = acc;
}

// ---------------------------------------------------------------------------
// Kernel 7: deterministic final reduction (mean over batch)
// ---------------------------------------------------------------------------
__global__ void final_k(float* ws, float* out) {
  if (threadIdx.x == 0 && blockIdx.x == 0) {
    const float* part = (const float*)((const char*)ws + OFF_PART);
    float s = 0.f;
    for (int i = 0; i < NPROB; ++i) s += part[i];
    out[0] = s / (float)NB;
  }
}

extern "C" void kernel_launch(void* const* d_in, const int* in_sizes, int n_in,
                              void* d_out, int out_size, void* d_ws, size_t ws_size,
                              hipStream_t stream) {
  const float* in = (const float*)d_in[0];
  float* ws = (float*)d_ws;
  float* out = (float*)d_out;
  hipLaunchKernelGGL(resize_k, dim3((NB * NV + 255) / 256), dim3(256), 0, stream, in, ws);
  hipLaunchKernelGGL(label_rename_k, dim3(NPROB), dim3(256), 0, stream, ws);
  hipLaunchKernelGGL(hash_k, dim3(NPROB), dim3(256), 0, stream, ws);
  hipLaunchKernelGGL(quantile_k, dim3(NPROB * KB), dim3(256), 0, stream, ws);
  hipLaunchKernelGGL(kruskal_bucket_k, dim3(NPROB * KB), dim3(256), 0, stream, ws);
  hipLaunchKernelGGL(topk_k, dim3(NPROB), dim3(256), 0, stream, ws);
  hipLaunchKernelGGL(final_k, dim3(1), dim3(64), 0, stream, ws, out);
}

// Round 8
// 841.492 us; speedup vs baseline: 1.2193x; 1.2193x over previous
//
#include <hip/hip_runtime.h>
#include <math.h>

#define NB 16
#define INW 256
#define GN 100
#define NV (GN*GN)          // 10000
#define NPROB (NB*2)        // 32
#define K_TOP 20
#define HSZ 8192
#define HMASK (HSZ-1)
#define EMPTYK 0xFFFFFFFFu
#define KB 32               // rank buckets per problem
#define RCAP 5120           // max regions per problem
#define MYCAP 256           // max edges per bucket (= ceil(HSZ/KB))
#define LISTCAP 4096        // max bars per problem (bars <= R-1)

// ws byte offsets (total 6,843,904 B — within proven ws budget)
#define OFF_RES   0               // NB*NV f32 = 640000
#define OFF_LAB   640000          // NPROB*NV u16 = 640000
#define OFF_DENSE 1280000         // NPROB*NV u16 = 640000
#define OFF_ROOTV 1920000         // NPROB*RCAP u16 = 327680
#define OFF_RORD  2247680         // NPROB*RCAP u64 = 1310720
#define OFF_D2B   3558400         // NPROB*RCAP f32 = 655360
#define OFF_EDGES 4213760         // NPROB*HSZ u64 = 2097152
#define OFF_ECNT  6310912         // NPROB u32
#define OFF_RCNT  6311040         // NPROB u32
#define OFF_QUANT 6311168         // NPROB*32 u64 = 8192
#define OFF_LCNT  6319360         // NPROB u32
#define OFF_LIST  6319488         // NPROB*LISTCAP f32 = 524288
#define OFF_PART  6843776         // NPROB f32

__device__ __forceinline__ int imin(int a, int b){ return a < b ? a : b; }
__device__ __forceinline__ int imax(int a, int b){ return a > b ? a : b; }

__device__ __forceinline__ unsigned mono32(float f){
  unsigned b = __float_as_uint(f);
  return (b & 0x80000000u) ? ~b : (b | 0x80000000u);
}
__device__ __forceinline__ float unmono(unsigned m){
  unsigned b = (m & 0x80000000u) ? (m ^ 0x80000000u) : ~m;
  return __uint_as_float(b);
}

// path-halving find on volatile LDS parent array (concurrent-safe: all
// writes point to ancestors)
__device__ __forceinline__ unsigned uf_find(volatile unsigned* par, unsigned x){
  unsigned p = par[x];
  while (p != x) {
    unsigned g = par[p];
    if (g != p) par[x] = g;
    x = g;
    p = par[x];
  }
  return x;
}

// keys-cubic a=-0.5 weights (renormalized over valid taps)
__device__ __forceinline__ void cub_w(int i, int& j0, float w[4]) {
  double inv = (double)INW / (double)GN;
  double sf  = ((double)i + 0.5) * inv - 0.5;
  j0 = (int)floor(sf) - 1;
  double wd[4]; double s = 0.0;
  #pragma unroll
  for (int k = 0; k < 4; ++k) {
    int j = j0 + k;
    double t = fabs(sf - (double)j);
    double v;
    if (t < 1.0)      v = ((1.5*t - 2.5)*t)*t + 1.0;
    else if (t < 2.0) v = ((-0.5*t + 2.5)*t - 4.0)*t + 2.0;
    else              v = 0.0;
    if (j < 0 || j >= INW) v = 0.0;
    wd[k] = v; s += v;
  }
  #pragma unroll
  for (int k = 0; k < 4; ++k) w[k] = (float)(wd[k] / s);
}

// ---------------------------------------------------------------------------
// Kernel 1: separable bicubic resize 256x256 -> 100x100
// ---------------------------------------------------------------------------
__global__ __launch_bounds__(256) void resize_k(const float* __restrict__ in, float* ws) {
  float* outp = (float*)((char*)ws + OFF_RES);
  int idx = blockIdx.x * 256 + threadIdx.x;
  if (idx >= NB * NV) return;
  int b = idx / NV; int rem = idx - b * NV;
  int i = rem / GN; int j = rem - i * GN;
  const float* img = in + (size_t)b * INW * INW;
  int r0, c0; float wr[4], wc[4];
  cub_w(i, r0, wr);
  cub_w(j, c0, wc);
  float acc = 0.f;
  #pragma unroll
  for (int kr = 0; kr < 4; ++kr) {
    int rr = imin(imax(r0 + kr, 0), INW - 1);
    const float* row = img + rr * INW;
    int c0c = imin(imax(c0 + 0, 0), INW - 1);
    int c1c = imin(imax(c0 + 1, 0), INW - 1);
    int c2c = imin(imax(c0 + 2, 0), INW - 1);
    int c3c = imin(imax(c0 + 3, 0), INW - 1);
    float rs = wc[0]*row[c0c] + wc[1]*row[c1c] + wc[2]*row[c2c] + wc[3]*row[c3c];
    acc += wr[kr] * rs;
  }
  outp[idx] = acc;
}

// ---------------------------------------------------------------------------
// Kernel 2: watershed labels + root compaction (NO ranking here)
// ---------------------------------------------------------------------------
__global__ __launch_bounds__(256) void label_k(float* ws) {
  __shared__ unsigned sm[NV];                 // 40KB
  __shared__ unsigned short lab[NV];          // 20KB
  __shared__ unsigned cnt[256];
  int p = blockIdx.x, samp = p >> 1, neg = p & 1, tid = threadIdx.x;
  const float* res = (const float*)((const char*)ws + OFF_RES) + samp * NV;
  unsigned short* glab = (unsigned short*)((char*)ws + OFF_LAB) + (size_t)p * NV;
  unsigned short* rootv = (unsigned short*)((char*)ws + OFF_ROOTV) + (size_t)p * RCAP;
  unsigned long long* rord = (unsigned long long*)((char*)ws + OFF_RORD) + (size_t)p * RCAP;
  unsigned* rcnt = (unsigned*)((char*)ws + OFF_RCNT);
  float sgn = neg ? -1.f : 1.f;
  for (int i = tid; i < NV; i += 256) sm[i] = mono32(sgn * res[i]);
  __syncthreads();
  const int nd = neg ? 4 : 6;
  for (int v = tid; v < NV; v += 256) {
    int r = v / GN, c = v - r * GN;
    unsigned long long best = ((unsigned long long)sm[v] << 32) | (unsigned)~(unsigned)v;
    unsigned bi = (unsigned)v;
    bool cb[6] = { c < GN-1, c > 0, r < GN-1, r > 0,
                   (r < GN-1) && (c < GN-1), (r > 0) && (c > 0) };
    int  off[6] = { 1, -1, GN, -GN, GN+1, -(GN+1) };
    #pragma unroll
    for (int d = 0; d < 6; ++d) {
      if (d < nd && cb[d]) {
        unsigned y = (unsigned)(v + off[d]);
        unsigned long long o = ((unsigned long long)sm[y] << 32) | (unsigned)~y;
        if (o > best) { best = o; bi = y; }
      }
    }
    lab[v] = (unsigned short)bi;
  }
  __syncthreads();
  for (int v = tid; v < NV; v += 256) {
    unsigned r = lab[v];
    while (1) { unsigned n = lab[r]; if (n == r) break; r = n; }
    lab[v] = (unsigned short)r;
    glab[v] = (unsigned short)r;
  }
  __syncthreads();
  // compact roots to global (order = compaction order; ranked later)
  unsigned my = 0;
  for (int v = tid; v < NV; v += 256) if (lab[v] == (unsigned short)v) ++my;
  cnt[tid] = my;
  __syncthreads();
  for (int off = 1; off < 256; off <<= 1) {
    unsigned t = (tid >= off) ? cnt[tid - off] : 0u;
    __syncthreads();
    cnt[tid] += t;
    __syncthreads();
  }
  unsigned base = cnt[tid] - my;
  for (int v = tid; v < NV; v += 256) {
    if (lab[v] == (unsigned short)v) {
      if (base < RCAP) {
        rootv[base] = (unsigned short)v;
        rord[base] = ((unsigned long long)sm[v] << 32) | (unsigned)~(unsigned)v;
      }
      ++base;
    }
  }
  if (tid == 255) rcnt[p] = (cnt[255] > RCAP) ? RCAP : cnt[255];
}

// ---------------------------------------------------------------------------
// Kernel 3: rank roots desc (elder order) -> dense ids + birth table.
// 4 slices per problem for parallelism; rord cached in LDS.
// ---------------------------------------------------------------------------
__global__ __launch_bounds__(256) void rank_root_k(float* ws) {
  __shared__ unsigned long long ro[RCAP];     // 40KB
  int p = blockIdx.x / 4, sl = blockIdx.x % 4, tid = threadIdx.x;
  const unsigned short* rootv = (const unsigned short*)((const char*)ws + OFF_ROOTV) + (size_t)p * RCAP;
  const unsigned long long* rord = (const unsigned long long*)((const char*)ws + OFF_RORD) + (size_t)p * RCAP;
  unsigned short* dense = (unsigned short*)((char*)ws + OFF_DENSE) + (size_t)p * NV;
  float* d2b = (float*)((char*)ws + OFF_D2B) + (size_t)p * RCAP;
  const unsigned* rcnt = (const unsigned*)((const char*)ws + OFF_RCNT);
  unsigned R = rcnt[p];
  for (unsigned i = tid; i < R; i += 256) ro[i] = rord[i];
  __syncthreads();
  unsigned RS = (R + 3) / 4;
  unsigned lo = sl * RS, hi = lo + RS; if (hi > R) hi = R;
  for (unsigned i = lo + tid; i < hi; i += 256) {
    unsigned long long oi = ro[i];
    unsigned r = 0;
    for (unsigned j = 0; j < R; ++j) r += (ro[j] > oi) ? 1u : 0u;
    dense[rootv[i]] = (unsigned short)r;
    d2b[r] = unmono((unsigned)(oi >> 32));
  }
}

// ---------------------------------------------------------------------------
// Kernel 4: boundary-edge hashing (dense pids, u32 events) + compaction
// ---------------------------------------------------------------------------
__global__ __launch_bounds__(256) void hash_k(float* ws) {
  __shared__ unsigned sm[NV];                 // 40KB
  __shared__ unsigned hkey[HSZ];              // 32KB
  __shared__ unsigned hval[HSZ];              // 32KB
  __shared__ unsigned short dlab[NV];         // 20KB (dense-composed labels)
  __shared__ unsigned cnt[256];
  int p = blockIdx.x, samp = p >> 1, neg = p & 1, tid = threadIdx.x;
  const float* res = (const float*)((const char*)ws + OFF_RES) + samp * NV;
  const unsigned short* glab = (const unsigned short*)((const char*)ws + OFF_LAB) + (size_t)p * NV;
  const unsigned short* gdense = (const unsigned short*)((const char*)ws + OFF_DENSE) + (size_t)p * NV;
  unsigned long long* gedges = (unsigned long long*)((char*)ws + OFF_EDGES) + (size_t)p * HSZ;
  unsigned* ecnt = (unsigned*)((char*)ws + OFF_ECNT);
  unsigned* lcnt = (unsigned*)((char*)ws + OFF_LCNT);
  unsigned long long* quant = (unsigned long long*)((char*)ws + OFF_QUANT) + p * 32;
  float sgn = neg ? -1.f : 1.f;
  for (int i = tid; i < NV; i += 256) {
    sm[i] = mono32(sgn * res[i]);
    dlab[i] = gdense[glab[i]];
  }
  for (int s = tid; s < HSZ; s += 256) { hkey[s] = EMPTYK; hval[s] = 0u; }
  if (tid == 0) lcnt[p] = 0u;
  if (tid < 32) quant[tid] = (tid == 0) ? ~0ull : 0ull;
  __syncthreads();
  for (int v = tid; v < NV; v += 256) {
    int r = v / GN, c = v - r * GN;
    unsigned a = dlab[v];
    unsigned sv = sm[v];
    bool vb[3] = { c < GN-1, r < GN-1, (!neg) && (r < GN-1) && (c < GN-1) };
    int  vo[3] = { 1, GN, GN+1 };
    #pragma unroll
    for (int d = 0; d < 3; ++d) {
      if (vb[d]) {
        unsigned w = (unsigned)(v + vo[d]);
        unsigned b = dlab[w];
        if (a != b) {
          unsigned sw = sm[w];
          unsigned ev = (sv < sw) ? sv : sw;
          unsigned dlo = (a < b) ? a : b, dhi = (a < b) ? b : a;
          unsigned pid = (dlo << 16) | dhi;
          unsigned h = (pid * 2654435761u) >> 19;
          for (int pr2 = 0; pr2 < HSZ; ++pr2) {
            unsigned k = hkey[h];
            if (k == EMPTYK) {
              unsigned old = atomicCAS(&hkey[h], EMPTYK, pid);
              k = (old == EMPTYK) ? pid : old;
            }
            if (k == pid) { atomicMax(&hval[h], ev); break; }
            h = (h + 1) & HMASK;
          }
        }
      }
    }
  }
  __syncthreads();
  unsigned my = 0;
  for (int s = tid; s < HSZ; s += 256) if (hkey[s] != EMPTYK) ++my;
  cnt[tid] = my;
  __syncthreads();
  for (int off = 1; off < 256; off <<= 1) {
    unsigned t = (tid >= off) ? cnt[tid - off] : 0u;
    __syncthreads();
    cnt[tid] += t;
    __syncthreads();
  }
  unsigned base = cnt[tid] - my;
  for (int s = tid; s < HSZ; s += 256) {
    if (hkey[s] != EMPTYK) {
      gedges[base++] = ((unsigned long long)hval[s] << 32) | hkey[s];
    }
  }
  if (tid == 255) ecnt[p] = cnt[255];
}

// ---------------------------------------------------------------------------
// Kernel 5: exact rank-quantile splitters (32 slices/problem, unique u64s)
// ---------------------------------------------------------------------------
__global__ __launch_bounds__(256) void quantile_k(float* ws) {
  __shared__ unsigned long long items[HSZ];   // 64KB
  int p = blockIdx.x / KB, sl = blockIdx.x % KB, tid = threadIdx.x;
  const unsigned long long* gedges = (const unsigned long long*)((const char*)ws + OFF_EDGES) + (size_t)p * HSZ;
  const unsigned* ecnt = (const unsigned*)((const char*)ws + OFF_ECNT);
  unsigned long long* quant = (unsigned long long*)((char*)ws + OFF_QUANT) + p * 32;
  unsigned E = ecnt[p]; if (E > HSZ) E = HSZ;
  for (unsigned i = tid; i < E; i += 256) items[i] = gedges[i];
  __syncthreads();
  unsigned chunk = (E + KB - 1) / KB;
  unsigned base = sl * chunk;
  for (unsigned e = base + tid; e < base + chunk && e < E; e += 256) {
    unsigned long long x = items[e];
    unsigned r = 0;
    for (unsigned j = 0; j < E; ++j) r += (items[j] > x) ? 1u : 0u;
    if (r >= chunk && (r % chunk) == 0) {
      unsigned m = r / chunk;
      if (m < KB) quant[m] = x;
    }
  }
}

// ---------------------------------------------------------------------------
// Kernel 6: bucketed elder-rule Kruskal, one-pass lock-free CC.
// One block per (problem, bucket). prefix = {it > quant[bk]} streamed once
// with CAS hooks (min dense id root == elder); own <= 256 edges rank-sorted;
// serial Kruskal on lane 0. birth values read from L2 on merges only.
// ---------------------------------------------------------------------------
__global__ __launch_bounds__(256) void kruskal_bucket_k(float* ws) {
  __shared__ unsigned long long my[MYCAP];      // 2KB
  __shared__ unsigned long long my2[MYCAP + 1]; // 2KB
  __shared__ unsigned par[RCAP];                // 20KB
  __shared__ unsigned mycnt;
  int p = blockIdx.x / KB, bk = blockIdx.x % KB, tid = threadIdx.x;
  const unsigned long long* gedges = (const unsigned long long*)((const char*)ws + OFF_EDGES) + (size_t)p * HSZ;
  const float* d2b = (const float*)((const char*)ws + OFF_D2B) + (size_t)p * RCAP;
  const unsigned* ecnt = (const unsigned*)((const char*)ws + OFF_ECNT);
  const unsigned* rcnt = (const unsigned*)((const char*)ws + OFF_RCNT);
  const unsigned long long* quant = (const unsigned long long*)((const char*)ws + OFF_QUANT) + p * 32;
  unsigned* lcnt = (unsigned*)((char*)ws + OFF_LCNT);
  float* glist = (float*)((char*)ws + OFF_LIST) + (size_t)p * LISTCAP;
  unsigned E = ecnt[p]; if (E > HSZ) E = HSZ;
  unsigned R = rcnt[p]; if (R > RCAP) R = RCAP;
  unsigned long long qup = quant[bk];
  unsigned long long qdn = (bk == KB-1) ? 0ull : quant[bk + 1];
  if (tid == 0) mycnt = 0;
  for (unsigned d = tid; d < R; d += 256) par[d] = d;
  __syncthreads();
  volatile unsigned* vpar = par;
  // single streamed pass: gather own edges + one-pass CC over prefix
  for (unsigned e = tid; e < E; e += 256) {
    unsigned long long it = gedges[e];
    if (it > qup) {
      // prefix edge: lock-free union (hook larger root under smaller)
      unsigned pid = (unsigned)it;
      unsigned a = pid >> 16, b = pid & 0xffffu;
      while (1) {
        unsigned ra = uf_find(vpar, a);
        unsigned rb = uf_find(vpar, b);
        if (ra == rb) break;
        unsigned lo = (ra < rb) ? ra : rb, hi = (ra < rb) ? rb : ra;
        if (atomicCAS(&par[hi], hi, lo) == hi) break;
        a = lo; b = hi;
      }
    } else if (it > qdn) {
      unsigned k = atomicAdd(&mycnt, 1u);
      my[k] = it;
    }
  }
  __syncthreads();
  // one compression sweep so serial finds are short
  for (unsigned d = tid; d < R; d += 256) {
    unsigned r = d;
    while (vpar[r] != r) r = vpar[r];
    par[d] = r;
  }
  unsigned mc = mycnt;
  if (tid == 0) my2[mc] = 0ull;
  // local rank sort desc (items unique)
  for (unsigned i = tid; i < mc; i += 256) {
    unsigned long long x = my[i];
    unsigned r = 0;
    for (unsigned j = 0; j < mc; ++j) r += (my[j] > x) ? 1u : 0u;
    my2[r] = x;
  }
  __syncthreads();
  // serial Kruskal; winner = min dense id (elder by construction)
  if (tid != 0) return;
  unsigned long long it = my2[0];
  for (unsigned e = 0; e < mc; ++e) {
    unsigned long long nx = my2[e + 1];
    unsigned ev = (unsigned)(it >> 32);
    unsigned pid = (unsigned)it;
    unsigned ca = pid >> 16, cb = pid & 0xffffu;
    while (1) {
      unsigned pa = par[ca], pb = par[cb];
      bool da = (pa == ca), db = (pb == cb);
      if (da && db) break;
      unsigned ga = par[pa], gb = par[pb];
      if (!da) { par[ca] = ga; ca = ga; }
      if (!db) { par[cb] = gb; cb = gb; }
    }
    if (ca != cb) {
      unsigned win = (ca < cb) ? ca : cb;
      unsigned los = (ca < cb) ? cb : ca;
      float bar = d2b[los] - unmono(ev);        // L2 read on merges only
      unsigned idx = atomicAdd(&lcnt[p], 1u);
      if (idx < LISTCAP) glist[idx] = bar;
      par[los] = win;
    }
    it = nx;
  }
}

// ---------------------------------------------------------------------------
// Kernel 7: per-problem top-20 over compact bar list -> partial[p]
// ---------------------------------------------------------------------------
__global__ __launch_bounds__(256) void topk_k(float* ws) {
  __shared__ float sl[LISTCAP];
  __shared__ float rv[256];
  __shared__ int   ri[256];
  int p = blockIdx.x, tid = threadIdx.x;
  const float* glist = (const float*)((const char*)ws + OFF_LIST) + (size_t)p * LISTCAP;
  const unsigned* lcnt = (const unsigned*)((const char*)ws + OFF_LCNT);
  float* part = (float*)((char*)ws + OFF_PART);
  unsigned cnt = lcnt[p]; if (cnt > LISTCAP) cnt = LISTCAP;
  for (unsigned i = tid; i < cnt; i += 256) sl[i] = glist[i];
  __syncthreads();
  float acc = 0.f;
  for (int k = 0; k < K_TOP; ++k) {
    float mv = -1.f; int mi = LISTCAP;
    for (unsigned i = tid; i < cnt; i += 256) {
      float v = sl[i];
      if (v > mv) { mv = v; mi = (int)i; }
    }
    rv[tid] = mv; ri[tid] = mi;
    __syncthreads();
    for (int s = 128; s > 0; s >>= 1) {
      if (tid < s) {
        if (rv[tid+s] > rv[tid] || (rv[tid+s] == rv[tid] && ri[tid+s] < ri[tid])) {
          rv[tid] = rv[tid+s]; ri[tid] = ri[tid+s];
        }
      }
      __syncthreads();
    }
    if (tid == 0) {
      float best = rv[0] > 0.f ? rv[0] : 0.f;   // pad with zeros like reference
      float sgnk = (k < 5) ? -1.f : 1.f;
      acc += sgnk * best * best;
      if (ri[0] < LISTCAP) sl[ri[0]] = -2.f;
    }
    __syncthreads();
  }
  if (tid == 0) part[p] = acc;
}

// ---------------------------------------------------------------------------
// Kernel 8: deterministic final reduction (mean over batch)
// ---------------------------------------------------------------------------
__global__ void final_k(float* ws, float* out) {
  if (threadIdx.x == 0 && blockIdx.x == 0) {
    const float* part = (const float*)((const char*)ws + OFF_PART);
    float s = 0.f;
    for (int i = 0; i < NPROB; ++i) s += part[i];
    out[0] = s / (float)NB;
  }
}

extern "C" void kernel_launch(void* const* d_in, const int* in_sizes, int n_in,
                              void* d_out, int out_size, void* d_ws, size_t ws_size,
                              hipStream_t stream) {
  const float* in = (const float*)d_in[0];
  float* ws = (float*)d_ws;
  float* out = (float*)d_out;
  hipLaunchKernelGGL(resize_k, dim3((NB * NV + 255) / 256), dim3(256), 0, stream, in, ws);
  hipLaunchKernelGGL(label_k, dim3(NPROB), dim3(256), 0, stream, ws);
  hipLaunchKernelGGL(rank_root_k, dim3(NPROB * 4), dim3(256), 0, stream, ws);
  hipLaunchKernelGGL(hash_k, dim3(NPROB), dim3(256), 0, stream, ws);
  hipLaunchKernelGGL(quantile_k, dim3(NPROB * KB), dim3(256), 0, stream, ws);
  hipLaunchKernelGGL(kruskal_bucket_k, dim3(NPROB * KB), dim3(256), 0, stream, ws);
  hipLaunchKernelGGL(topk_k, dim3(NPROB), dim3(256), 0, stream, ws);
  hipLaunchKernelGGL(final_k, dim3(1), dim3(64), 0, stream, ws, out);
}